// Round 1
// baseline (67.199 us; speedup 1.0000x reference)
//
#include <hip/hip_runtime.h>
#include <math.h>

#define S_ 32
#define B_ 128
#define M_ 128
#define F_ 512
#define C_ 100
#define SG 4            // s-samples per block in contrib kernel
#define NG (S_ / SG)    // 8 s-groups
#define NBB 4           // b rows per contrib block (512 threads)

// ws layout (floats):
//   eta     [B_*M_]        @ 0
//   ep      [C_*M_]        @ B_*M_           = exp(+2*beta)
//   en      [C_*M_]        @ B_*M_ + C_*M_   = exp(-2*beta)
//   partial [NG*B_*M_]     @ B_*M_ + 2*C_*M_
#define WS_ETA  0
#define WS_EP   (B_*M_)
#define WS_EN   (B_*M_ + C_*M_)
#define WS_PART (B_*M_ + 2*C_*M_)

// Kernel 1: eta = sigmoid(alpha_0 + x @ alpha.T)  (blocks 0..B_-1)
//           ep/en tables                          (blocks B_..B_+99)
__global__ __launch_bounds__(128) void k_eta_tab(
    const float* __restrict__ x, const float* __restrict__ alpha0,
    const float* __restrict__ alpha, const float* __restrict__ beta,
    float* __restrict__ ws) {
  int bid = blockIdx.x;
  int t = threadIdx.x;  // 0..127
  if (bid < B_) {
    __shared__ __align__(16) float xs[F_];
    // 512 floats / 128 threads = one float4 each
    ((float4*)xs)[t] = ((const float4*)(x + (size_t)bid * F_))[t];
    __syncthreads();
    int m = t;
    const float4* ar = (const float4*)(alpha + (size_t)m * F_);
    float acc = 0.f;
#pragma unroll 4
    for (int j = 0; j < F_ / 4; ++j) {
      float4 a = ar[j];
      float4 xv = ((const float4*)xs)[j];
      acc = fmaf(a.x, xv.x, acc);
      acc = fmaf(a.y, xv.y, acc);
      acc = fmaf(a.z, xv.z, acc);
      acc = fmaf(a.w, xv.w, acc);
    }
    float l = alpha0[m] + acc;
    ws[WS_ETA + bid * M_ + m] = 1.f / (1.f + expf(-l));
  } else {
    int i = (bid - B_) * 128 + t;  // exactly C_*M_ = 12800 slots
    if (i < C_ * M_) {
      float bv = beta[i];
      ws[WS_EP + i] = expf(2.f * bv);
      ws[WS_EN + i] = expf(-2.f * bv);
    }
  }
}

// Kernel 2: per (s-group, b-quad) compute contributions, accumulate over SG
// samples, write partial[g][b][m].
__global__ __launch_bounds__(512) void k_contrib(
    const float* __restrict__ Z, const int* __restrict__ y,
    const float* __restrict__ beta0, const float* __restrict__ beta,
    const float* __restrict__ ws, float* __restrict__ partial) {
  int g = blockIdx.x;                 // 0..NG-1
  int bq = blockIdx.y;                // 0..B_/NBB-1
  int t = threadIdx.x;                // 0..511
  int bl = t >> 7;                    // 0..3 sub-block (one b each)
  int m = t & 127;                    // m index; doubles as c index (c<100)
  int b = bq * NBB + bl;

  const float* eta = ws + WS_ETA;
  const float* ep = ws + WS_EP;
  const float* en = ws + WS_EN;

  __shared__ __align__(16) float zsh[NBB][M_];
  __shared__ float esh[NBB][C_];
  __shared__ float red[NBB][128];

  int yb = y[b];
  float eta_bm = eta[b * M_ + m];
  float one_m_eta = 1.f - eta_bm;
  float acc = 0.f;

  for (int si = 0; si < SG; ++si) {
    int s = g * SG + si;
    zsh[bl][m] = Z[((size_t)s * B_ + b) * M_ + m];
    __syncthreads();

    // base[c] = beta_0[c] + sum_m Z[s,b,m] * beta[c,m]   (c = m, c < C_)
    float base = -1e30f;
    if (m < C_) {
      const float4* br = (const float4*)(beta + (size_t)m * M_);
      const float4* z4 = (const float4*)zsh[bl];
      float a = 0.f;
#pragma unroll
      for (int j = 0; j < M_ / 4; ++j) {
        float4 bb = br[j];
        float4 zz = z4[j];
        a = fmaf(bb.x, zz.x, a);
        a = fmaf(bb.y, zz.y, a);
        a = fmaf(bb.z, zz.z, a);
        a = fmaf(bb.w, zz.w, a);
      }
      base = beta0[m] + a;
    }

    // max over c (per sub-block)
    red[bl][m] = base;
    __syncthreads();
    for (int off = 64; off > 0; off >>= 1) {
      if (m < off) red[bl][m] = fmaxf(red[bl][m], red[bl][m + off]);
      __syncthreads();
    }
    float mb = red[bl][0];
    __syncthreads();  // all reads of red[..][0] done before overwrite

    float e0 = (m < C_) ? expf(base - mb) : 0.f;
    if (m < C_) esh[bl][m] = e0;
    red[bl][m] = e0;
    __syncthreads();
    for (int off = 64; off > 0; off >>= 1) {
      if (m < off) red[bl][m] += red[bl][m + off];
      __syncthreads();
    }
    float den0 = red[bl][0];
    float e0y = esh[bl][yb];
    float pi0 = e0y / den0;

    // den_p/den_n for this m: sum_c E0[c] * exp(+/-2*beta[c,m])
    float accp = 0.f, accn = 0.f;
    const float* epm = ep + m;
    const float* enm = en + m;
#pragma unroll 4
    for (int c = 0; c < C_; ++c) {
      float e = esh[bl][c];
      accp = fmaf(e, epm[c * M_], accp);
      accn = fmaf(e, enm[c * M_], accn);
    }

    float z = zsh[bl][m];
    float contrib;
    if (z > 0.f) {
      // pi_pos = pi0 ; pi_neg uses shift -2*beta -> en
      float pin = e0y * en[yb * M_ + m] / accn;
      contrib = fmaf(pi0, eta_bm, pin * one_m_eta);
    } else {
      // pi_neg = pi0 ; pi_pos uses shift +2*beta -> ep
      float pip = e0y * ep[yb * M_ + m] / accp;
      contrib = fmaf(pip, eta_bm, pi0 * one_m_eta);
    }
    acc += contrib;
    __syncthreads();  // protect zsh/esh before next iteration overwrites
  }

  partial[((size_t)g * B_ + b) * M_ + m] = acc;
}

// Kernel 3: out[b,m] = sum_g partial[g][b][m]
__global__ __launch_bounds__(256) void k_reduce(const float* __restrict__ partial,
                                                float* __restrict__ out) {
  int i = blockIdx.x * 256 + threadIdx.x;
  if (i < B_ * M_) {
    float a = 0.f;
#pragma unroll
    for (int gi = 0; gi < NG; ++gi) a += partial[(size_t)gi * B_ * M_ + i];
    out[i] = a;
  }
}

extern "C" void kernel_launch(void* const* d_in, const int* in_sizes, int n_in,
                              void* d_out, int out_size, void* d_ws, size_t ws_size,
                              hipStream_t stream) {
  const float* x = (const float*)d_in[0];
  const int* y = (const int*)d_in[1];
  const float* Z = (const float*)d_in[2];
  const float* alpha0 = (const float*)d_in[3];
  const float* alpha = (const float*)d_in[4];
  const float* beta0 = (const float*)d_in[5];
  const float* beta = (const float*)d_in[6];
  float* ws = (float*)d_ws;
  float* out = (float*)d_out;
  float* partial = ws + WS_PART;

  // K1: eta (128 blocks) + ep/en tables (100 blocks)
  k_eta_tab<<<dim3(B_ + (C_ * M_ + 127) / 128), dim3(128), 0, stream>>>(
      x, alpha0, alpha, beta, ws);
  // K2: contributions, partial sums over s-groups
  k_contrib<<<dim3(NG, B_ / NBB), dim3(512), 0, stream>>>(Z, y, beta0, beta, ws,
                                                          partial);
  // K3: final reduce over s-groups
  k_reduce<<<dim3((B_ * M_ + 255) / 256), dim3(256), 0, stream>>>(partial, out);
}